// Round 8
// baseline (192.021 us; speedup 1.0000x reference)
//
#include <hip/hip_runtime.h>

// Problem constants
static constexpr int Bc = 64;     // batch
static constexpr int Nc = 4096;   // set size
static constexpr int Dc = 128;    // d_in
static constexpr int Mc = 1024;   // num ref points
static constexpr int Lc = 128;    // num projections

using short8   = __attribute__((ext_vector_type(8))) short;
using ushort8v = __attribute__((ext_vector_type(8))) unsigned short;
using f32x4    = __attribute__((ext_vector_type(4))) float;

__device__ __forceinline__ unsigned short f2bf(float x) {
  unsigned u = __builtin_bit_cast(unsigned, x);
  return (unsigned short)((u + 0x7FFFu + ((u >> 16) & 1u)) >> 16);
}
__device__ __forceinline__ float bf2f(unsigned short h) {
  unsigned u = ((unsigned)h) << 16;
  return __builtin_bit_cast(float, u);
}

__device__ __forceinline__ int swz(int i) { return i ^ ((i >> 4) & 31); }

// ---------------------------------------------------------------------------
// Kernel 1 (setup): per l-block (128 blocks x 256 threads):
//   - Wh/Wl[l][d] = bf16 hi/lo split of theta_v[l]/||theta_v[l]||
//   - C[l] = sum_m ref[m,l]*weight[l,m]
//   - v[l][n]: binning-rank argsort of ref column + interp stencil scatter
// ---------------------------------------------------------------------------
__global__ __launch_bounds__(256) void setup_kernel(
    const float* __restrict__ theta_v, const float* __restrict__ ref,
    const float* __restrict__ weight, unsigned short* __restrict__ Wh,
    unsigned short* __restrict__ Wl, float* __restrict__ C,
    float* __restrict__ v) {
  constexpr int NBv = 2048;
  constexpr float LOv = -4.2f;
  constexpr float SCv = (float)NBv / 8.4f;

  __shared__ int pref[NBv];            // 8 KB
  __shared__ float skey[Mc];           // 4 KB
  __shared__ unsigned short sidx[Mc];  // 2 KB
  __shared__ float vrow[Nc];           // 16 KB
  __shared__ int wsum[4];
  __shared__ float s2[2];
  __shared__ float c4[4];

  int l = blockIdx.x;
  int tid = threadIdx.x;
  int lane = tid & 63, wv = tid >> 6;

  // ref column (also reused for C)
  float x[4];
  #pragma unroll
  for (int j = 0; j < 4; ++j) x[j] = ref[(size_t)(tid + 256 * j) * Lc + l];

  for (int i = tid; i < NBv; i += 256) pref[i] = 0;
  for (int i = tid; i < Nc; i += 256) vrow[i] = 0.f;

  // W-norm partial (threads 0..127; waves 0,1)
  float wval = 0.f;
  if (tid < Dc) {
    wval = theta_v[l * Dc + tid];
    float sq = wval * wval;
    #pragma unroll
    for (int off = 1; off < 64; off <<= 1) sq += __shfl_xor(sq, off, 64);
    if (lane == 0) s2[wv] = sq;
  }
  // C partial (all threads, reuses x)
  {
    float cacc = 0.f;
    #pragma unroll
    for (int j = 0; j < 4; ++j) cacc += x[j] * weight[(size_t)l * Mc + tid + 256 * j];
    #pragma unroll
    for (int off = 1; off < 64; off <<= 1) cacc += __shfl_xor(cacc, off, 64);
    if (lane == 0) c4[wv] = cacc;
  }
  __syncthreads();

  if (tid < Dc) {
    float norm = sqrtf(s2[0] + s2[1]);
    float val = wval / norm;
    unsigned short hi = f2bf(val);
    Wh[l * Dc + tid] = hi;
    Wl[l * Dc + tid] = f2bf(val - bf2f(hi));
  }
  if (tid == 0) C[l] = c4[0] + c4[1] + c4[2] + c4[3];

  // histogram
  int bb[4];
  #pragma unroll
  for (int j = 0; j < 4; ++j) {
    int bi = (int)((x[j] - LOv) * SCv);
    bi = bi < 0 ? 0 : (bi > NBv - 1 ? NBv - 1 : bi);
    bb[j] = bi;
    atomicAdd(&pref[swz(bi)], 1);
  }
  __syncthreads();

  // exclusive prefix over 2048 bins (8/thread)
  {
    int base_ = tid * 8;
    int loc[8]; int s = 0;
    #pragma unroll
    for (int j = 0; j < 8; ++j) loc[j] = pref[swz(base_ + j)];
    #pragma unroll
    for (int j = 0; j < 8; ++j) { int c = loc[j]; loc[j] = s; s += c; }
    int inc = s;
    #pragma unroll
    for (int off = 1; off < 64; off <<= 1) {
      int o = __shfl_up(inc, off, 64);
      if (lane >= off) inc += o;
    }
    if (lane == 63) wsum[wv] = inc;
    __syncthreads();
    int wbase = 0;
    #pragma unroll
    for (int ww = 0; ww < 4; ++ww) if (ww < wv) wbase += wsum[ww];
    int tbase = wbase + inc - s;
    #pragma unroll
    for (int j = 0; j < 8; ++j) pref[swz(base_ + j)] = tbase + loc[j];
  }
  __syncthreads();

  // scatter (value, orig idx)
  #pragma unroll
  for (int j = 0; j < 4; ++j) {
    int p = atomicAdd(&pref[swz(bb[j])], 1);
    skey[p] = x[j];
    sidx[p] = (unsigned short)(tid + 256 * j);
  }
  __syncthreads();

  // position-ordered exact rank (stable: (value, orig idx)) + stencil scatter
  #pragma unroll
  for (int k = 0; k < 4; ++k) {
    int p = tid + 256 * k;
    float y = skey[p];
    int m = sidx[p];
    int b = (int)((y - LOv) * SCv);
    b = b < 0 ? 0 : (b > NBv - 1 ? NBv - 1 : b);
    int lo_ = b ? pref[swz(b - 1)] : 0;
    int hi_ = pref[swz(b)];
    int r = lo_;
    for (int q = lo_; q < hi_; ++q) {
      float z = skey[q];
      r += (z < y || (z == y && sidx[q] < m)) ? 1 : 0;
    }
    // element with original index m has rank r in the stable argsort
    float wvv = weight[(size_t)l * Mc + r];
    double pos = (double)(m + 1) * (double)(Nc + 1) / (double)(Mc + 1) - 1.0;
    int i0 = (int)pos;
    float t = (float)(pos - (double)i0);
    atomicAdd(&vrow[i0], (1.0f - t) * wvv);
    atomicAdd(&vrow[i0 + 1], t * wvv);
  }
  __syncthreads();
  for (int i = tid; i < Nc; i += 256) v[(size_t)l * Nc + i] = vrow[i];
}

// ---------------------------------------------------------------------------
// Kernel 2 (v3): MFMA GEMM, f32 = bf16 hi + lo (3-term).
//  512 threads = 8 waves; wave wv owns 16 n-rows x 128 l.
//  A: each lane loads its 2x(4 chunk) row-slices ONCE up-front (coalesced),
//     converts per chunk in-register. B: double-buffered LDS (40 KB), loads
//     issued one chunk ahead into registers; ONE barrier per chunk.
// sl[bloc][l][n] = sum_d X[bloc,n,d] * W[l,d]
// ---------------------------------------------------------------------------
__global__ __launch_bounds__(512) void gemm_kernel(
    const float* __restrict__ X, const unsigned short* __restrict__ Whp,
    const unsigned short* __restrict__ Wlp, float* __restrict__ sl) {
  __shared__ unsigned short Bh[2][128][40];  // 20 KB
  __shared__ unsigned short Bl[2][128][40];  // 20 KB

  int bloc = blockIdx.y;
  int nbase = blockIdx.x * 128;
  int tid = threadIdx.x;
  int lane = tid & 63;
  int wv = tid >> 6;       // wave 0..7 -> 16 n-rows each
  int m16 = lane & 15;
  int kg = lane >> 4;

  // B staging: one 8-u16 segment per thread per array
  int brow = tid >> 2;
  int bc = (tid & 3) * 8;
  const unsigned short* gbh = Whp + (size_t)brow * Dc + bc;
  const unsigned short* gbl = Wlp + (size_t)brow * Dc + bc;

  // ---- A: full kg-slice of the lane's row, all 4 chunks, up-front
  const float* arow = X + ((size_t)bloc * Nc + nbase + wv * 16 + m16) * Dc + kg * 8;
  float4 af[4][2];
  #pragma unroll
  for (int c = 0; c < 4; ++c) {
    af[c][0] = *(const float4*)(arow + c * 32);
    af[c][1] = *(const float4*)(arow + c * 32 + 4);
  }

  // prologue: B chunk 0 -> buf0; B chunk 1 -> regs
  ushort8v rbh = *(const ushort8v*)gbh;
  ushort8v rbl = *(const ushort8v*)gbl;
  *(ushort8v*)&Bh[0][brow][bc] = rbh;
  *(ushort8v*)&Bl[0][brow][bc] = rbl;
  rbh = *(const ushort8v*)(gbh + 32);
  rbl = *(const ushort8v*)(gbl + 32);

  f32x4 acc[8] = {};
  __syncthreads();  // buf0 visible

  #pragma unroll
  for (int c = 0; c < 4; ++c) {
    // write chunk c+1 into the other buffer (its old readers finished at
    // the barrier ending iteration c-1); then refill regs with chunk c+2
    if (c < 3) {
      *(ushort8v*)&Bh[(c + 1) & 1][brow][bc] = rbh;
      *(ushort8v*)&Bl[(c + 1) & 1][brow][bc] = rbl;
    }
    if (c < 2) {
      rbh = *(const ushort8v*)(gbh + (c + 2) * 32);
      rbl = *(const ushort8v*)(gbl + (c + 2) * 32);
    }

    // convert A chunk c
    float xs[8] = {af[c][0].x, af[c][0].y, af[c][0].z, af[c][0].w,
                   af[c][1].x, af[c][1].y, af[c][1].z, af[c][1].w};
    short8 ah, al;
    #pragma unroll
    for (int e = 0; e < 8; ++e) {
      unsigned short h = f2bf(xs[e]);
      ah[e] = (short)h;
      al[e] = (short)f2bf(xs[e] - bf2f(h));
    }

    #pragma unroll
    for (int u = 0; u < 8; ++u) {
      short8 bh = *(const short8*)&Bh[c & 1][u * 16 + m16][kg * 8];
      short8 bl = *(const short8*)&Bl[c & 1][u * 16 + m16][kg * 8];
      acc[u] = __builtin_amdgcn_mfma_f32_16x16x32_bf16(ah, bh, acc[u], 0, 0, 0);
      acc[u] = __builtin_amdgcn_mfma_f32_16x16x32_bf16(ah, bl, acc[u], 0, 0, 0);
      acc[u] = __builtin_amdgcn_mfma_f32_16x16x32_bf16(al, bh, acc[u], 0, 0, 0);
    }
    __syncthreads();
  }

  // write-out: C/D col = m16 (l), row = kg*4 + reg (n)
  #pragma unroll
  for (int u = 0; u < 8; ++u) {
    int l = u * 16 + m16;
    int n0 = nbase + wv * 16 + kg * 4;
    float* dst = sl + ((size_t)bloc * Lc + l) * Nc + n0;
    *(float4*)dst = *(float4*)&acc[u];
  }
}

// ---------------------------------------------------------------------------
// Kernel 3 (v6): radix-rank + fused dot, 512 threads.
//  - single atomic pass: histogram atomicAdd return = within-bin slot;
//    scatter pos = exclusive-prefix + slot (pref stays EXCLUSIVE)
//  - element-ordered rank pass reusing registered x/bb/pos (no skey
//    re-read, no bin recompute)
// ---------------------------------------------------------------------------
__global__ __launch_bounds__(512, 8) void rank_dot_kernel(
    const float* __restrict__ sl, const float* __restrict__ v,
    const float* __restrict__ C, float* __restrict__ out, int b0) {
  constexpr int NB = 4096;
  constexpr float LO = -4.2f;
  constexpr float SCALE = (float)NB / 8.4f;
  constexpr int NT = 512;
  constexpr int EL = Nc / NT;  // 8 elements per thread

  __shared__ int pref[NB];       // hist -> EXCLUSIVE prefix; then red
  __shared__ float skey[Nc];     // (wsum during scan) bin-ordered keys
  int* wsum = (int*)skey;        // live only during scan (before skey writes)
  float* red = (float*)pref;     // live only after final barrier

  int l = blockIdx.x & (Lc - 1);
  int bloc = blockIdx.x >> 7;
  int tid = threadIdx.x;
  const float* src = sl + ((size_t)bloc * Lc + l) * Nc;

  // coalesced strided load: thread owns float4s {tid + 512*j}
  float x[EL];
  {
    const float4* s4 = (const float4*)src;
    #pragma unroll
    for (int j = 0; j < EL / 4; ++j) {
      float4 f = s4[tid + NT * j];
      x[j * 4 + 0] = f.x; x[j * 4 + 1] = f.y;
      x[j * 4 + 2] = f.z; x[j * 4 + 3] = f.w;
    }
  }

  for (int i = tid; i < NB; i += NT) pref[i] = 0;
  __syncthreads();

  // histogram; returned old count = within-bin slot
  int bb[EL];
  int ofs[EL];
  #pragma unroll
  for (int j = 0; j < EL; ++j) {
    int bi = (int)((x[j] - LO) * SCALE);
    bi = bi < 0 ? 0 : (bi > NB - 1 ? NB - 1 : bi);
    bb[j] = bi;
    ofs[j] = atomicAdd(&pref[swz(bi)], 1);
  }
  __syncthreads();

  // exclusive prefix sum over 4096 bins (8 bins/thread)
  {
    int base_ = tid * 8;
    int loc[8]; int s = 0;
    #pragma unroll
    for (int j = 0; j < 8; ++j) loc[j] = pref[swz(base_ + j)];
    #pragma unroll
    for (int j = 0; j < 8; ++j) { int c = loc[j]; loc[j] = s; s += c; }
    int lane = tid & 63, wvv = tid >> 6;
    int inc = s;
    #pragma unroll
    for (int off = 1; off < 64; off <<= 1) {
      int o = __shfl_up(inc, off, 64);
      if (lane >= off) inc += o;
    }
    if (lane == 63) wsum[wvv] = inc;
    __syncthreads();
    int wbase = 0;
    #pragma unroll
    for (int ww = 0; ww < 8; ++ww) if (ww < wvv) wbase += wsum[ww];
    int tbase = wbase + inc - s;  // exclusive across threads
    #pragma unroll
    for (int j = 0; j < 8; ++j) pref[swz(base_ + j)] = tbase + loc[j];
  }
  __syncthreads();

  // scatter: pos = exclusive-prefix + slot (NO second atomic; pref unchanged)
  int pos[EL];
  #pragma unroll
  for (int j = 0; j < EL; ++j) {
    pos[j] = pref[swz(bb[j])] + ofs[j];
    skey[pos[j]] = x[j];
  }
  __syncthreads();

  // element-ordered rank + fused dot. Rank = segment start + strict-less
  // count + equal-with-smaller-scatter-pos count (bijective within ties;
  // ties are bitwise-equal values so the dot sum is assignment-invariant).
  const float* vrow = v + (size_t)l * Nc;
  float acc = 0.f;
  #pragma unroll
  for (int j = 0; j < EL; ++j) {
    float y = x[j];
    int b = bb[j];
    int p = pos[j];
    int lo_ = pref[swz(b)];
    int hi_ = (b == NB - 1) ? Nc : pref[swz(b + 1)];
    int r = lo_;
    for (int q = lo_; q < hi_; ++q) {
      float z = skey[q];
      r += (z < y || (z == y && q < p)) ? 1 : 0;
    }
    acc += y * vrow[r];
  }

  #pragma unroll
  for (int off = 1; off < 64; off <<= 1) acc += __shfl_xor(acc, off, 64);
  __syncthreads();  // all pref reads done before red (aliased) is written
  if ((tid & 63) == 0) red[tid >> 6] = acc;
  __syncthreads();
  if (tid == 0) {
    float t = 0.f;
    #pragma unroll
    for (int ww = 0; ww < 8; ++ww) t += red[ww];
    int b = b0 + bloc;
    out[(size_t)b * Lc + l] = C[l] - t;
  }
}

// ---------------------------------------------------------------------------
extern "C" void kernel_launch(void* const* d_in, const int* in_sizes, int n_in,
                              void* d_out, int out_size, void* d_ws, size_t ws_size,
                              hipStream_t stream) {
  const float* X       = (const float*)d_in[0];  // [B,N,D]
  const float* theta_v = (const float*)d_in[1];  // [L,D]
  const float* ref     = (const float*)d_in[2];  // [M,L]
  const float* weight  = (const float*)d_in[3];  // [L,M]
  float* out = (float*)d_out;                    // [B,L]

  // workspace layout: v [L*N] f32 | Wh,Wl [L*D] u16 | C [128] f32 | sl
  float* v  = (float*)d_ws;
  unsigned short* Wh = (unsigned short*)(v + (size_t)Lc * Nc);
  unsigned short* Wl = Wh + (size_t)Lc * Dc;
  float* Cc = (float*)(Wl + (size_t)Lc * Dc);
  float* sl = Cc + 128;
  size_t used = (size_t)((char*)sl - (char*)d_ws);
  size_t per_b = (size_t)Lc * Nc * sizeof(float);  // 2 MB per batch element
  int chunk = 1;
  if (ws_size > used + per_b) {
    size_t c = (ws_size - used) / per_b;
    chunk = (int)(c > (size_t)Bc ? (size_t)Bc : c);
    if (chunk < 1) chunk = 1;
  }

  setup_kernel<<<Lc, 256, 0, stream>>>(theta_v, ref, weight, Wh, Wl, Cc, v);

  for (int b0 = 0; b0 < Bc; b0 += chunk) {
    int nb = (Bc - b0) < chunk ? (Bc - b0) : chunk;
    dim3 g1(Nc / 128, nb);
    gemm_kernel<<<g1, 512, 0, stream>>>(X + (size_t)b0 * Nc * Dc, Wh, Wl, sl);
    rank_dot_kernel<<<(size_t)nb * Lc, 512, 0, stream>>>(sl, v, Cc, out, b0);
  }
}

// Round 9
// 160.141 us; speedup vs baseline: 1.1991x; 1.1991x over previous
//
#include <hip/hip_runtime.h>

// Problem constants
static constexpr int Bc = 64;     // batch
static constexpr int Nc = 4096;   // set size
static constexpr int Dc = 128;    // d_in
static constexpr int Mc = 1024;   // num ref points
static constexpr int Lc = 128;    // num projections

using short8   = __attribute__((ext_vector_type(8))) short;
using ushort8v = __attribute__((ext_vector_type(8))) unsigned short;
using f32x4    = __attribute__((ext_vector_type(4))) float;

__device__ __forceinline__ unsigned short f2bf(float x) {
  unsigned u = __builtin_bit_cast(unsigned, x);
  return (unsigned short)((u + 0x7FFFu + ((u >> 16) & 1u)) >> 16);
}
__device__ __forceinline__ float bf2f(unsigned short h) {
  unsigned u = ((unsigned)h) << 16;
  return __builtin_bit_cast(float, u);
}

__device__ __forceinline__ int swz(int i) { return i ^ ((i >> 4) & 31); }

// ---------------------------------------------------------------------------
// Kernel 1 (setup): per l-block (128 blocks x 256 threads):
//   - Wh/Wl[l][d] = bf16 hi/lo split of theta_v[l]/||theta_v[l]||
//   - C[l] = sum_m ref[m,l]*weight[l,m]
//   - v[l][n]: binning-rank argsort of ref column + interp stencil scatter
// ---------------------------------------------------------------------------
__global__ __launch_bounds__(256) void setup_kernel(
    const float* __restrict__ theta_v, const float* __restrict__ ref,
    const float* __restrict__ weight, unsigned short* __restrict__ Wh,
    unsigned short* __restrict__ Wl, float* __restrict__ C,
    float* __restrict__ v) {
  constexpr int NBv = 2048;
  constexpr float LOv = -4.2f;
  constexpr float SCv = (float)NBv / 8.4f;

  __shared__ int pref[NBv];            // 8 KB
  __shared__ float skey[Mc];           // 4 KB
  __shared__ unsigned short sidx[Mc];  // 2 KB
  __shared__ float vrow[Nc];           // 16 KB
  __shared__ int wsum[4];
  __shared__ float s2[2];
  __shared__ float c4[4];

  int l = blockIdx.x;
  int tid = threadIdx.x;
  int lane = tid & 63, wv = tid >> 6;

  // ref column (also reused for C)
  float x[4];
  #pragma unroll
  for (int j = 0; j < 4; ++j) x[j] = ref[(size_t)(tid + 256 * j) * Lc + l];

  for (int i = tid; i < NBv; i += 256) pref[i] = 0;
  for (int i = tid; i < Nc; i += 256) vrow[i] = 0.f;

  // W-norm partial (threads 0..127; waves 0,1)
  float wval = 0.f;
  if (tid < Dc) {
    wval = theta_v[l * Dc + tid];
    float sq = wval * wval;
    #pragma unroll
    for (int off = 1; off < 64; off <<= 1) sq += __shfl_xor(sq, off, 64);
    if (lane == 0) s2[wv] = sq;
  }
  // C partial (all threads, reuses x)
  {
    float cacc = 0.f;
    #pragma unroll
    for (int j = 0; j < 4; ++j) cacc += x[j] * weight[(size_t)l * Mc + tid + 256 * j];
    #pragma unroll
    for (int off = 1; off < 64; off <<= 1) cacc += __shfl_xor(cacc, off, 64);
    if (lane == 0) c4[wv] = cacc;
  }
  __syncthreads();

  if (tid < Dc) {
    float norm = sqrtf(s2[0] + s2[1]);
    float val = wval / norm;
    unsigned short hi = f2bf(val);
    Wh[l * Dc + tid] = hi;
    Wl[l * Dc + tid] = f2bf(val - bf2f(hi));
  }
  if (tid == 0) C[l] = c4[0] + c4[1] + c4[2] + c4[3];

  // histogram
  int bb[4];
  #pragma unroll
  for (int j = 0; j < 4; ++j) {
    int bi = (int)((x[j] - LOv) * SCv);
    bi = bi < 0 ? 0 : (bi > NBv - 1 ? NBv - 1 : bi);
    bb[j] = bi;
    atomicAdd(&pref[swz(bi)], 1);
  }
  __syncthreads();

  // exclusive prefix over 2048 bins (8/thread)
  {
    int base_ = tid * 8;
    int loc[8]; int s = 0;
    #pragma unroll
    for (int j = 0; j < 8; ++j) loc[j] = pref[swz(base_ + j)];
    #pragma unroll
    for (int j = 0; j < 8; ++j) { int c = loc[j]; loc[j] = s; s += c; }
    int inc = s;
    #pragma unroll
    for (int off = 1; off < 64; off <<= 1) {
      int o = __shfl_up(inc, off, 64);
      if (lane >= off) inc += o;
    }
    if (lane == 63) wsum[wv] = inc;
    __syncthreads();
    int wbase = 0;
    #pragma unroll
    for (int ww = 0; ww < 4; ++ww) if (ww < wv) wbase += wsum[ww];
    int tbase = wbase + inc - s;
    #pragma unroll
    for (int j = 0; j < 8; ++j) pref[swz(base_ + j)] = tbase + loc[j];
  }
  __syncthreads();

  // scatter (value, orig idx)
  #pragma unroll
  for (int j = 0; j < 4; ++j) {
    int p = atomicAdd(&pref[swz(bb[j])], 1);
    skey[p] = x[j];
    sidx[p] = (unsigned short)(tid + 256 * j);
  }
  __syncthreads();

  // position-ordered exact rank (stable: (value, orig idx)) + stencil scatter
  #pragma unroll
  for (int k = 0; k < 4; ++k) {
    int p = tid + 256 * k;
    float y = skey[p];
    int m = sidx[p];
    int b = (int)((y - LOv) * SCv);
    b = b < 0 ? 0 : (b > NBv - 1 ? NBv - 1 : b);
    int lo_ = b ? pref[swz(b - 1)] : 0;
    int hi_ = pref[swz(b)];
    int r = lo_;
    for (int q = lo_; q < hi_; ++q) {
      float z = skey[q];
      r += (z < y || (z == y && sidx[q] < m)) ? 1 : 0;
    }
    // element with original index m has rank r in the stable argsort
    float wvv = weight[(size_t)l * Mc + r];
    double pos = (double)(m + 1) * (double)(Nc + 1) / (double)(Mc + 1) - 1.0;
    int i0 = (int)pos;
    float t = (float)(pos - (double)i0);
    atomicAdd(&vrow[i0], (1.0f - t) * wvv);
    atomicAdd(&vrow[i0 + 1], t * wvv);
  }
  __syncthreads();
  for (int i = tid; i < Nc; i += 256) v[(size_t)l * Nc + i] = vrow[i];
}

// ---------------------------------------------------------------------------
// Kernel 2 (v3): MFMA GEMM, f32 = bf16 hi + lo (3-term).
//  512 threads = 8 waves; wave wv owns 16 n-rows x 128 l.
//  A: lane loads its row-slices once up-front (coalesced), converts per
//  chunk in-register. B: double-buffered LDS; one barrier per chunk.
// sl[bloc][l][n] = sum_d X[bloc,n,d] * W[l,d]
// ---------------------------------------------------------------------------
__global__ __launch_bounds__(512) void gemm_kernel(
    const float* __restrict__ X, const unsigned short* __restrict__ Whp,
    const unsigned short* __restrict__ Wlp, float* __restrict__ sl) {
  __shared__ unsigned short Bh[2][128][40];  // 20 KB
  __shared__ unsigned short Bl[2][128][40];  // 20 KB

  int bloc = blockIdx.y;
  int nbase = blockIdx.x * 128;
  int tid = threadIdx.x;
  int lane = tid & 63;
  int wv = tid >> 6;       // wave 0..7 -> 16 n-rows each
  int m16 = lane & 15;
  int kg = lane >> 4;

  // B staging: one 8-u16 segment per thread per array
  int brow = tid >> 2;
  int bc = (tid & 3) * 8;
  const unsigned short* gbh = Whp + (size_t)brow * Dc + bc;
  const unsigned short* gbl = Wlp + (size_t)brow * Dc + bc;

  // ---- A: full kg-slice of the lane's row, all 4 chunks, up-front
  const float* arow = X + ((size_t)bloc * Nc + nbase + wv * 16 + m16) * Dc + kg * 8;
  float4 af[4][2];
  #pragma unroll
  for (int c = 0; c < 4; ++c) {
    af[c][0] = *(const float4*)(arow + c * 32);
    af[c][1] = *(const float4*)(arow + c * 32 + 4);
  }

  // prologue: B chunk 0 -> buf0; B chunk 1 -> regs
  ushort8v rbh = *(const ushort8v*)gbh;
  ushort8v rbl = *(const ushort8v*)gbl;
  *(ushort8v*)&Bh[0][brow][bc] = rbh;
  *(ushort8v*)&Bl[0][brow][bc] = rbl;
  rbh = *(const ushort8v*)(gbh + 32);
  rbl = *(const ushort8v*)(gbl + 32);

  f32x4 acc[8] = {};
  __syncthreads();  // buf0 visible

  #pragma unroll
  for (int c = 0; c < 4; ++c) {
    if (c < 3) {
      *(ushort8v*)&Bh[(c + 1) & 1][brow][bc] = rbh;
      *(ushort8v*)&Bl[(c + 1) & 1][brow][bc] = rbl;
    }
    if (c < 2) {
      rbh = *(const ushort8v*)(gbh + (c + 2) * 32);
      rbl = *(const ushort8v*)(gbl + (c + 2) * 32);
    }

    // convert A chunk c
    float xs[8] = {af[c][0].x, af[c][0].y, af[c][0].z, af[c][0].w,
                   af[c][1].x, af[c][1].y, af[c][1].z, af[c][1].w};
    short8 ah, al;
    #pragma unroll
    for (int e = 0; e < 8; ++e) {
      unsigned short h = f2bf(xs[e]);
      ah[e] = (short)h;
      al[e] = (short)f2bf(xs[e] - bf2f(h));
    }

    #pragma unroll
    for (int u = 0; u < 8; ++u) {
      short8 bh = *(const short8*)&Bh[c & 1][u * 16 + m16][kg * 8];
      short8 bl = *(const short8*)&Bl[c & 1][u * 16 + m16][kg * 8];
      acc[u] = __builtin_amdgcn_mfma_f32_16x16x32_bf16(ah, bh, acc[u], 0, 0, 0);
      acc[u] = __builtin_amdgcn_mfma_f32_16x16x32_bf16(ah, bl, acc[u], 0, 0, 0);
      acc[u] = __builtin_amdgcn_mfma_f32_16x16x32_bf16(al, bh, acc[u], 0, 0, 0);
    }
    __syncthreads();
  }

  // write-out: C/D col = m16 (l), row = kg*4 + reg (n)
  #pragma unroll
  for (int u = 0; u < 8; ++u) {
    int l = u * 16 + m16;
    int n0 = nbase + wv * 16 + kg * 4;
    float* dst = sl + ((size_t)bloc * Lc + l) * Nc + n0;
    *(float4*)dst = *(float4*)&acc[u];
  }
}

// ---------------------------------------------------------------------------
// Kernel 3 (v7): radix-rank + fused dot, 512 threads.
//  = v5's POSITION-ORDERED rank pass (broadcast-friendly, convergent)
//  + v6's single atomic pass (histogram atomicAdd return = within-bin slot,
//    pref stays EXCLUSIVE).
// ---------------------------------------------------------------------------
__global__ __launch_bounds__(512, 8) void rank_dot_kernel(
    const float* __restrict__ sl, const float* __restrict__ v,
    const float* __restrict__ C, float* __restrict__ out, int b0) {
  constexpr int NB = 4096;
  constexpr float LO = -4.2f;
  constexpr float SCALE = (float)NB / 8.4f;
  constexpr int NT = 512;
  constexpr int EL = Nc / NT;  // 8 elements per thread

  __shared__ int pref[NB];       // hist -> EXCLUSIVE prefix; then red
  __shared__ float skey[Nc];     // (wsum during scan) bin-ordered keys
  int* wsum = (int*)skey;        // live only during scan (before skey writes)
  float* red = (float*)pref;     // live only after final barrier

  int l = blockIdx.x & (Lc - 1);
  int bloc = blockIdx.x >> 7;
  int tid = threadIdx.x;
  const float* src = sl + ((size_t)bloc * Lc + l) * Nc;

  // coalesced strided load: thread owns float4s {tid + 512*j}
  float x[EL];
  {
    const float4* s4 = (const float4*)src;
    #pragma unroll
    for (int j = 0; j < EL / 4; ++j) {
      float4 f = s4[tid + NT * j];
      x[j * 4 + 0] = f.x; x[j * 4 + 1] = f.y;
      x[j * 4 + 2] = f.z; x[j * 4 + 3] = f.w;
    }
  }

  for (int i = tid; i < NB; i += NT) pref[i] = 0;
  __syncthreads();

  // histogram; returned old count = within-bin slot
  int bb[EL];
  int ofs[EL];
  #pragma unroll
  for (int j = 0; j < EL; ++j) {
    int bi = (int)((x[j] - LO) * SCALE);
    bi = bi < 0 ? 0 : (bi > NB - 1 ? NB - 1 : bi);
    bb[j] = bi;
    ofs[j] = atomicAdd(&pref[swz(bi)], 1);
  }
  __syncthreads();

  // exclusive prefix sum over 4096 bins (8 bins/thread)
  {
    int base_ = tid * 8;
    int loc[8]; int s = 0;
    #pragma unroll
    for (int j = 0; j < 8; ++j) loc[j] = pref[swz(base_ + j)];
    #pragma unroll
    for (int j = 0; j < 8; ++j) { int c = loc[j]; loc[j] = s; s += c; }
    int lane = tid & 63, wvv = tid >> 6;
    int inc = s;
    #pragma unroll
    for (int off = 1; off < 64; off <<= 1) {
      int o = __shfl_up(inc, off, 64);
      if (lane >= off) inc += o;
    }
    if (lane == 63) wsum[wvv] = inc;
    __syncthreads();
    int wbase = 0;
    #pragma unroll
    for (int ww = 0; ww < 8; ++ww) if (ww < wvv) wbase += wsum[ww];
    int tbase = wbase + inc - s;  // exclusive across threads
    #pragma unroll
    for (int j = 0; j < 8; ++j) pref[swz(base_ + j)] = tbase + loc[j];
  }
  __syncthreads();

  // scatter: pos = exclusive-prefix + slot (no second atomic; pref unchanged)
  #pragma unroll
  for (int j = 0; j < EL; ++j) {
    skey[pref[swz(bb[j])] + ofs[j]] = x[j];
  }
  __syncthreads();

  // POSITION-ORDERED rank + fused dot: thread handles sorted-side positions
  // p = tid + 512k (coalesced skey read; adjacent lanes share segments ->
  // broadcast reads + convergent trip counts). Bin recomputed from value
  // (pure function -> consistent). Tie-break by scatter position q<p:
  // bijective within ties; ties are bitwise-equal values so the dot sum is
  // assignment-invariant -> deterministic output.
  const float* vrow = v + (size_t)l * Nc;
  float acc = 0.f;
  #pragma unroll
  for (int k = 0; k < EL; ++k) {
    int p = tid + NT * k;
    float y = skey[p];
    int b = (int)((y - LO) * SCALE);
    b = b < 0 ? 0 : (b > NB - 1 ? NB - 1 : b);
    int lo_ = pref[swz(b)];
    int hi_ = (b == NB - 1) ? Nc : pref[swz(b + 1)];
    int r = lo_;
    for (int q = lo_; q < hi_; ++q) {
      float z = skey[q];
      r += (z < y || (z == y && q < p)) ? 1 : 0;
    }
    acc += y * vrow[r];
  }

  #pragma unroll
  for (int off = 1; off < 64; off <<= 1) acc += __shfl_xor(acc, off, 64);
  __syncthreads();  // all pref reads done before red (aliased) is written
  if ((tid & 63) == 0) red[tid >> 6] = acc;
  __syncthreads();
  if (tid == 0) {
    float t = 0.f;
    #pragma unroll
    for (int ww = 0; ww < 8; ++ww) t += red[ww];
    int b = b0 + bloc;
    out[(size_t)b * Lc + l] = C[l] - t;
  }
}

// ---------------------------------------------------------------------------
extern "C" void kernel_launch(void* const* d_in, const int* in_sizes, int n_in,
                              void* d_out, int out_size, void* d_ws, size_t ws_size,
                              hipStream_t stream) {
  const float* X       = (const float*)d_in[0];  // [B,N,D]
  const float* theta_v = (const float*)d_in[1];  // [L,D]
  const float* ref     = (const float*)d_in[2];  // [M,L]
  const float* weight  = (const float*)d_in[3];  // [L,M]
  float* out = (float*)d_out;                    // [B,L]

  // workspace layout: v [L*N] f32 | Wh,Wl [L*D] u16 | C [128] f32 | sl
  float* v  = (float*)d_ws;
  unsigned short* Wh = (unsigned short*)(v + (size_t)Lc * Nc);
  unsigned short* Wl = Wh + (size_t)Lc * Dc;
  float* Cc = (float*)(Wl + (size_t)Lc * Dc);
  float* sl = Cc + 128;
  size_t used = (size_t)((char*)sl - (char*)d_ws);
  size_t per_b = (size_t)Lc * Nc * sizeof(float);  // 2 MB per batch element
  int chunk = 1;
  if (ws_size > used + per_b) {
    size_t c = (ws_size - used) / per_b;
    chunk = (int)(c > (size_t)Bc ? (size_t)Bc : c);
    if (chunk < 1) chunk = 1;
  }

  setup_kernel<<<Lc, 256, 0, stream>>>(theta_v, ref, weight, Wh, Wl, Cc, v);

  for (int b0 = 0; b0 < Bc; b0 += chunk) {
    int nb = (Bc - b0) < chunk ? (Bc - b0) : chunk;
    dim3 g1(Nc / 128, nb);
    gemm_kernel<<<g1, 512, 0, stream>>>(X + (size_t)b0 * Nc * Dc, Wh, Wl, sl);
    rank_dot_kernel<<<(size_t)nb * Lc, 512, 0, stream>>>(sl, v, Cc, out, b0);
  }
}

// Round 10
// 152.868 us; speedup vs baseline: 1.2561x; 1.0476x over previous
//
#include <hip/hip_runtime.h>

// Problem constants
static constexpr int Bc = 64;     // batch
static constexpr int Nc = 4096;   // set size
static constexpr int Dc = 128;    // d_in
static constexpr int Mc = 1024;   // num ref points
static constexpr int Lc = 128;    // num projections

using short8   = __attribute__((ext_vector_type(8))) short;
using ushort8v = __attribute__((ext_vector_type(8))) unsigned short;
using f32x4    = __attribute__((ext_vector_type(4))) float;

__device__ __forceinline__ unsigned short f2bf(float x) {
  unsigned u = __builtin_bit_cast(unsigned, x);
  return (unsigned short)((u + 0x7FFFu + ((u >> 16) & 1u)) >> 16);
}
__device__ __forceinline__ float bf2f(unsigned short h) {
  unsigned u = ((unsigned)h) << 16;
  return __builtin_bit_cast(float, u);
}

__device__ __forceinline__ int swz(int i) { return i ^ ((i >> 4) & 31); }

// ---------------------------------------------------------------------------
// Kernel 1 (setup): per l-block (128 blocks x 256 threads):
//   - Wh/Wl[l][d] = bf16 hi/lo split of theta_v[l]/||theta_v[l]||
//   - C[l] = sum_m ref[m,l]*weight[l,m]
//   - v[l][n]: binning-rank argsort of ref column + interp stencil scatter
// ---------------------------------------------------------------------------
__global__ __launch_bounds__(256) void setup_kernel(
    const float* __restrict__ theta_v, const float* __restrict__ ref,
    const float* __restrict__ weight, unsigned short* __restrict__ Wh,
    unsigned short* __restrict__ Wl, float* __restrict__ C,
    float* __restrict__ v) {
  constexpr int NBv = 2048;
  constexpr float LOv = -4.2f;
  constexpr float SCv = (float)NBv / 8.4f;

  __shared__ int pref[NBv];            // 8 KB
  __shared__ float skey[Mc];           // 4 KB
  __shared__ unsigned short sidx[Mc];  // 2 KB
  __shared__ float vrow[Nc];           // 16 KB
  __shared__ int wsum[4];
  __shared__ float s2[2];
  __shared__ float c4[4];

  int l = blockIdx.x;
  int tid = threadIdx.x;
  int lane = tid & 63, wv = tid >> 6;

  // ref column (also reused for C)
  float x[4];
  #pragma unroll
  for (int j = 0; j < 4; ++j) x[j] = ref[(size_t)(tid + 256 * j) * Lc + l];

  for (int i = tid; i < NBv; i += 256) pref[i] = 0;
  for (int i = tid; i < Nc; i += 256) vrow[i] = 0.f;

  // W-norm partial (threads 0..127; waves 0,1)
  float wval = 0.f;
  if (tid < Dc) {
    wval = theta_v[l * Dc + tid];
    float sq = wval * wval;
    #pragma unroll
    for (int off = 1; off < 64; off <<= 1) sq += __shfl_xor(sq, off, 64);
    if (lane == 0) s2[wv] = sq;
  }
  // C partial (all threads, reuses x)
  {
    float cacc = 0.f;
    #pragma unroll
    for (int j = 0; j < 4; ++j) cacc += x[j] * weight[(size_t)l * Mc + tid + 256 * j];
    #pragma unroll
    for (int off = 1; off < 64; off <<= 1) cacc += __shfl_xor(cacc, off, 64);
    if (lane == 0) c4[wv] = cacc;
  }
  __syncthreads();

  if (tid < Dc) {
    float norm = sqrtf(s2[0] + s2[1]);
    float val = wval / norm;
    unsigned short hi = f2bf(val);
    Wh[l * Dc + tid] = hi;
    Wl[l * Dc + tid] = f2bf(val - bf2f(hi));
  }
  if (tid == 0) C[l] = c4[0] + c4[1] + c4[2] + c4[3];

  // histogram
  int bb[4];
  #pragma unroll
  for (int j = 0; j < 4; ++j) {
    int bi = (int)((x[j] - LOv) * SCv);
    bi = bi < 0 ? 0 : (bi > NBv - 1 ? NBv - 1 : bi);
    bb[j] = bi;
    atomicAdd(&pref[swz(bi)], 1);
  }
  __syncthreads();

  // exclusive prefix over 2048 bins (8/thread)
  {
    int base_ = tid * 8;
    int loc[8]; int s = 0;
    #pragma unroll
    for (int j = 0; j < 8; ++j) loc[j] = pref[swz(base_ + j)];
    #pragma unroll
    for (int j = 0; j < 8; ++j) { int c = loc[j]; loc[j] = s; s += c; }
    int inc = s;
    #pragma unroll
    for (int off = 1; off < 64; off <<= 1) {
      int o = __shfl_up(inc, off, 64);
      if (lane >= off) inc += o;
    }
    if (lane == 63) wsum[wv] = inc;
    __syncthreads();
    int wbase = 0;
    #pragma unroll
    for (int ww = 0; ww < 4; ++ww) if (ww < wv) wbase += wsum[ww];
    int tbase = wbase + inc - s;
    #pragma unroll
    for (int j = 0; j < 8; ++j) pref[swz(base_ + j)] = tbase + loc[j];
  }
  __syncthreads();

  // scatter (value, orig idx)
  #pragma unroll
  for (int j = 0; j < 4; ++j) {
    int p = atomicAdd(&pref[swz(bb[j])], 1);
    skey[p] = x[j];
    sidx[p] = (unsigned short)(tid + 256 * j);
  }
  __syncthreads();

  // position-ordered exact rank (stable: (value, orig idx)) + stencil scatter
  #pragma unroll
  for (int k = 0; k < 4; ++k) {
    int p = tid + 256 * k;
    float y = skey[p];
    int m = sidx[p];
    int b = (int)((y - LOv) * SCv);
    b = b < 0 ? 0 : (b > NBv - 1 ? NBv - 1 : b);
    int lo_ = b ? pref[swz(b - 1)] : 0;
    int hi_ = pref[swz(b)];
    int r = lo_;
    for (int q = lo_; q < hi_; ++q) {
      float z = skey[q];
      r += (z < y || (z == y && sidx[q] < m)) ? 1 : 0;
    }
    // element with original index m has rank r in the stable argsort
    float wvv = weight[(size_t)l * Mc + r];
    double pos = (double)(m + 1) * (double)(Nc + 1) / (double)(Mc + 1) - 1.0;
    int i0 = (int)pos;
    float t = (float)(pos - (double)i0);
    atomicAdd(&vrow[i0], (1.0f - t) * wvv);
    atomicAdd(&vrow[i0 + 1], t * wvv);
  }
  __syncthreads();
  for (int i = tid; i < Nc; i += 256) v[(size_t)l * Nc + i] = vrow[i];
}

// ---------------------------------------------------------------------------
// Kernel 2: MFMA GEMM, f32 = bf16 hi + lo (3-term).
//  512 threads = 8 waves; wave wv owns 16 n-rows x 128 l.
//  A: lane loads its row-slices once up-front (coalesced), converts per
//  chunk in-register. B: double-buffered LDS; one barrier per chunk.
// sl[bloc][l][n] = sum_d X[bloc,n,d] * W[l,d]
// ---------------------------------------------------------------------------
__global__ __launch_bounds__(512) void gemm_kernel(
    const float* __restrict__ X, const unsigned short* __restrict__ Whp,
    const unsigned short* __restrict__ Wlp, float* __restrict__ sl) {
  __shared__ unsigned short Bh[2][128][40];  // 20 KB
  __shared__ unsigned short Bl[2][128][40];  // 20 KB

  int bloc = blockIdx.y;
  int nbase = blockIdx.x * 128;
  int tid = threadIdx.x;
  int lane = tid & 63;
  int wv = tid >> 6;       // wave 0..7 -> 16 n-rows each
  int m16 = lane & 15;
  int kg = lane >> 4;

  // B staging: one 8-u16 segment per thread per array
  int brow = tid >> 2;
  int bc = (tid & 3) * 8;
  const unsigned short* gbh = Whp + (size_t)brow * Dc + bc;
  const unsigned short* gbl = Wlp + (size_t)brow * Dc + bc;

  // ---- A: full kg-slice of the lane's row, all 4 chunks, up-front
  const float* arow = X + ((size_t)bloc * Nc + nbase + wv * 16 + m16) * Dc + kg * 8;
  float4 af[4][2];
  #pragma unroll
  for (int c = 0; c < 4; ++c) {
    af[c][0] = *(const float4*)(arow + c * 32);
    af[c][1] = *(const float4*)(arow + c * 32 + 4);
  }

  // prologue: B chunk 0 -> buf0; B chunk 1 -> regs
  ushort8v rbh = *(const ushort8v*)gbh;
  ushort8v rbl = *(const ushort8v*)gbl;
  *(ushort8v*)&Bh[0][brow][bc] = rbh;
  *(ushort8v*)&Bl[0][brow][bc] = rbl;
  rbh = *(const ushort8v*)(gbh + 32);
  rbl = *(const ushort8v*)(gbl + 32);

  f32x4 acc[8] = {};
  __syncthreads();  // buf0 visible

  #pragma unroll
  for (int c = 0; c < 4; ++c) {
    if (c < 3) {
      *(ushort8v*)&Bh[(c + 1) & 1][brow][bc] = rbh;
      *(ushort8v*)&Bl[(c + 1) & 1][brow][bc] = rbl;
    }
    if (c < 2) {
      rbh = *(const ushort8v*)(gbh + (c + 2) * 32);
      rbl = *(const ushort8v*)(gbl + (c + 2) * 32);
    }

    // convert A chunk c
    float xs[8] = {af[c][0].x, af[c][0].y, af[c][0].z, af[c][0].w,
                   af[c][1].x, af[c][1].y, af[c][1].z, af[c][1].w};
    short8 ah, al;
    #pragma unroll
    for (int e = 0; e < 8; ++e) {
      unsigned short h = f2bf(xs[e]);
      ah[e] = (short)h;
      al[e] = (short)f2bf(xs[e] - bf2f(h));
    }

    #pragma unroll
    for (int u = 0; u < 8; ++u) {
      short8 bh = *(const short8*)&Bh[c & 1][u * 16 + m16][kg * 8];
      short8 bl = *(const short8*)&Bl[c & 1][u * 16 + m16][kg * 8];
      acc[u] = __builtin_amdgcn_mfma_f32_16x16x32_bf16(ah, bh, acc[u], 0, 0, 0);
      acc[u] = __builtin_amdgcn_mfma_f32_16x16x32_bf16(ah, bl, acc[u], 0, 0, 0);
      acc[u] = __builtin_amdgcn_mfma_f32_16x16x32_bf16(al, bh, acc[u], 0, 0, 0);
    }
    __syncthreads();
  }

  // write-out: C/D col = m16 (l), row = kg*4 + reg (n)
  #pragma unroll
  for (int u = 0; u < 8; ++u) {
    int l = u * 16 + m16;
    int n0 = nbase + wv * 16 + kg * 4;
    float* dst = sl + ((size_t)bloc * Lc + l) * Nc + n0;
    *(float4*)dst = *(float4*)&acc[u];
  }
}

// ---------------------------------------------------------------------------
// Kernel 3 (v8): radix-rank + fused dot, 512 threads.
//  Balanced bins via inverse-CDF (logistic) binning: slice values are
//  exactly N(0,1), so bin = NB*sigma(1.702x) gives lambda~1 per bin
//  (uniform-value bins had lambda~3.35 at the center -> wave-max inner
//  trip count ~10; balanced -> ~5). Strictly monotone -> exact ranking.
// ---------------------------------------------------------------------------
__device__ __forceinline__ int gbin(float x) {
  constexpr int NB = 4096;
  // NB / (1 + exp(-1.702 x)) = NB / (1 + exp2(-2.45541 x))
  float t = __builtin_amdgcn_exp2f(x * -2.45541f);
  float r = __builtin_amdgcn_rcpf(1.0f + t);
  int bi = (int)((float)NB * r);
  return bi < 0 ? 0 : (bi > NB - 1 ? NB - 1 : bi);
}

__global__ __launch_bounds__(512, 8) void rank_dot_kernel(
    const float* __restrict__ sl, const float* __restrict__ v,
    const float* __restrict__ C, float* __restrict__ out, int b0) {
  constexpr int NB = 4096;
  constexpr int NT = 512;
  constexpr int EL = Nc / NT;  // 8 elements per thread

  __shared__ int pref[NB];       // hist -> EXCLUSIVE prefix; then red
  __shared__ float skey[Nc];     // (wsum during scan) bin-ordered keys
  int* wsum = (int*)skey;        // live only during scan (before skey writes)
  float* red = (float*)pref;     // live only after final barrier

  int l = blockIdx.x & (Lc - 1);
  int bloc = blockIdx.x >> 7;
  int tid = threadIdx.x;
  const float* src = sl + ((size_t)bloc * Lc + l) * Nc;

  // coalesced strided load: thread owns float4s {tid + 512*j}
  float x[EL];
  {
    const float4* s4 = (const float4*)src;
    #pragma unroll
    for (int j = 0; j < EL / 4; ++j) {
      float4 f = s4[tid + NT * j];
      x[j * 4 + 0] = f.x; x[j * 4 + 1] = f.y;
      x[j * 4 + 2] = f.z; x[j * 4 + 3] = f.w;
    }
  }

  for (int i = tid; i < NB; i += NT) pref[i] = 0;
  __syncthreads();

  // histogram; returned old count = within-bin slot
  int bb[EL];
  int ofs[EL];
  #pragma unroll
  for (int j = 0; j < EL; ++j) {
    int bi = gbin(x[j]);
    bb[j] = bi;
    ofs[j] = atomicAdd(&pref[swz(bi)], 1);
  }
  __syncthreads();

  // exclusive prefix sum over 4096 bins (8 bins/thread)
  {
    int base_ = tid * 8;
    int loc[8]; int s = 0;
    #pragma unroll
    for (int j = 0; j < 8; ++j) loc[j] = pref[swz(base_ + j)];
    #pragma unroll
    for (int j = 0; j < 8; ++j) { int c = loc[j]; loc[j] = s; s += c; }
    int lane = tid & 63, wvv = tid >> 6;
    int inc = s;
    #pragma unroll
    for (int off = 1; off < 64; off <<= 1) {
      int o = __shfl_up(inc, off, 64);
      if (lane >= off) inc += o;
    }
    if (lane == 63) wsum[wvv] = inc;
    __syncthreads();
    int wbase = 0;
    #pragma unroll
    for (int ww = 0; ww < 8; ++ww) if (ww < wvv) wbase += wsum[ww];
    int tbase = wbase + inc - s;  // exclusive across threads
    #pragma unroll
    for (int j = 0; j < 8; ++j) pref[swz(base_ + j)] = tbase + loc[j];
  }
  __syncthreads();

  // scatter: pos = exclusive-prefix + slot (no second atomic; pref unchanged)
  #pragma unroll
  for (int j = 0; j < EL; ++j) {
    skey[pref[swz(bb[j])] + ofs[j]] = x[j];
  }
  __syncthreads();

  // POSITION-ORDERED rank + fused dot: thread handles sorted-side positions
  // p = tid + 512k (coalesced skey read; adjacent lanes share segments ->
  // broadcast reads + convergent trip counts). Bin recomputed from value
  // (pure function -> consistent). Tie-break by scatter position q<p:
  // bijective within ties; ties are bitwise-equal values so the dot sum is
  // assignment-invariant -> deterministic output.
  const float* vrow = v + (size_t)l * Nc;
  float acc = 0.f;
  #pragma unroll
  for (int k = 0; k < EL; ++k) {
    int p = tid + NT * k;
    float y = skey[p];
    int b = gbin(y);
    int lo_ = pref[swz(b)];
    int hi_ = (b == NB - 1) ? Nc : pref[swz(b + 1)];
    int r = lo_;
    for (int q = lo_; q < hi_; ++q) {
      float z = skey[q];
      r += (z < y || (z == y && q < p)) ? 1 : 0;
    }
    acc += y * vrow[r];
  }

  #pragma unroll
  for (int off = 1; off < 64; off <<= 1) acc += __shfl_xor(acc, off, 64);
  __syncthreads();  // all pref reads done before red (aliased) is written
  if ((tid & 63) == 0) red[tid >> 6] = acc;
  __syncthreads();
  if (tid == 0) {
    float t = 0.f;
    #pragma unroll
    for (int ww = 0; ww < 8; ++ww) t += red[ww];
    int b = b0 + bloc;
    out[(size_t)b * Lc + l] = C[l] - t;
  }
}

// ---------------------------------------------------------------------------
extern "C" void kernel_launch(void* const* d_in, const int* in_sizes, int n_in,
                              void* d_out, int out_size, void* d_ws, size_t ws_size,
                              hipStream_t stream) {
  const float* X       = (const float*)d_in[0];  // [B,N,D]
  const float* theta_v = (const float*)d_in[1];  // [L,D]
  const float* ref     = (const float*)d_in[2];  // [M,L]
  const float* weight  = (const float*)d_in[3];  // [L,M]
  float* out = (float*)d_out;                    // [B,L]

  // workspace layout: v [L*N] f32 | Wh,Wl [L*D] u16 | C [128] f32 | sl
  float* v  = (float*)d_ws;
  unsigned short* Wh = (unsigned short*)(v + (size_t)Lc * Nc);
  unsigned short* Wl = Wh + (size_t)Lc * Dc;
  float* Cc = (float*)(Wl + (size_t)Lc * Dc);
  float* sl = Cc + 128;
  size_t used = (size_t)((char*)sl - (char*)d_ws);
  size_t per_b = (size_t)Lc * Nc * sizeof(float);  // 2 MB per batch element
  int chunk = 1;
  if (ws_size > used + per_b) {
    size_t c = (ws_size - used) / per_b;
    chunk = (int)(c > (size_t)Bc ? (size_t)Bc : c);
    if (chunk < 1) chunk = 1;
  }

  setup_kernel<<<Lc, 256, 0, stream>>>(theta_v, ref, weight, Wh, Wl, Cc, v);

  for (int b0 = 0; b0 < Bc; b0 += chunk) {
    int nb = (Bc - b0) < chunk ? (Bc - b0) : chunk;
    dim3 g1(Nc / 128, nb);
    gemm_kernel<<<g1, 512, 0, stream>>>(X + (size_t)b0 * Nc * Dc, Wh, Wl, sl);
    rank_dot_kernel<<<(size_t)nb * Lc, 512, 0, stream>>>(sl, v, Cc, out, b0);
  }
}

// Round 11
// 151.862 us; speedup vs baseline: 1.2644x; 1.0066x over previous
//
#include <hip/hip_runtime.h>

// Problem constants
static constexpr int Bc = 64;     // batch
static constexpr int Nc = 4096;   // set size
static constexpr int Dc = 128;    // d_in
static constexpr int Mc = 1024;   // num ref points
static constexpr int Lc = 128;    // num projections

using short8   = __attribute__((ext_vector_type(8))) short;
using ushort8v = __attribute__((ext_vector_type(8))) unsigned short;
using f32x4    = __attribute__((ext_vector_type(4))) float;

__device__ __forceinline__ unsigned short f2bf(float x) {
  unsigned u = __builtin_bit_cast(unsigned, x);
  return (unsigned short)((u + 0x7FFFu + ((u >> 16) & 1u)) >> 16);
}
__device__ __forceinline__ float bf2f(unsigned short h) {
  unsigned u = ((unsigned)h) << 16;
  return __builtin_bit_cast(float, u);
}

__device__ __forceinline__ int swz(int i) { return i ^ ((i >> 4) & 31); }

// ---------------------------------------------------------------------------
// Kernel 1 (setup): per l-block (128 blocks x 256 threads):
//   - Wh/Wl[l][d] = bf16 hi/lo split of theta_v[l]/||theta_v[l]||
//   - C[l] = sum_m ref[m,l]*weight[l,m]
//   - v[l][n]: binning-rank argsort of ref column + interp stencil scatter
// ---------------------------------------------------------------------------
__global__ __launch_bounds__(256) void setup_kernel(
    const float* __restrict__ theta_v, const float* __restrict__ ref,
    const float* __restrict__ weight, unsigned short* __restrict__ Wh,
    unsigned short* __restrict__ Wl, float* __restrict__ C,
    float* __restrict__ v) {
  constexpr int NBv = 2048;
  constexpr float LOv = -4.2f;
  constexpr float SCv = (float)NBv / 8.4f;

  __shared__ int pref[NBv];            // 8 KB
  __shared__ float skey[Mc];           // 4 KB
  __shared__ unsigned short sidx[Mc];  // 2 KB
  __shared__ float vrow[Nc];           // 16 KB
  __shared__ int wsum[4];
  __shared__ float s2[2];
  __shared__ float c4[4];

  int l = blockIdx.x;
  int tid = threadIdx.x;
  int lane = tid & 63, wv = tid >> 6;

  // ref column (also reused for C)
  float x[4];
  #pragma unroll
  for (int j = 0; j < 4; ++j) x[j] = ref[(size_t)(tid + 256 * j) * Lc + l];

  for (int i = tid; i < NBv; i += 256) pref[i] = 0;
  for (int i = tid; i < Nc; i += 256) vrow[i] = 0.f;

  // W-norm partial (threads 0..127; waves 0,1)
  float wval = 0.f;
  if (tid < Dc) {
    wval = theta_v[l * Dc + tid];
    float sq = wval * wval;
    #pragma unroll
    for (int off = 1; off < 64; off <<= 1) sq += __shfl_xor(sq, off, 64);
    if (lane == 0) s2[wv] = sq;
  }
  // C partial (all threads, reuses x)
  {
    float cacc = 0.f;
    #pragma unroll
    for (int j = 0; j < 4; ++j) cacc += x[j] * weight[(size_t)l * Mc + tid + 256 * j];
    #pragma unroll
    for (int off = 1; off < 64; off <<= 1) cacc += __shfl_xor(cacc, off, 64);
    if (lane == 0) c4[wv] = cacc;
  }
  __syncthreads();

  if (tid < Dc) {
    float norm = sqrtf(s2[0] + s2[1]);
    float val = wval / norm;
    unsigned short hi = f2bf(val);
    Wh[l * Dc + tid] = hi;
    Wl[l * Dc + tid] = f2bf(val - bf2f(hi));
  }
  if (tid == 0) C[l] = c4[0] + c4[1] + c4[2] + c4[3];

  // histogram
  int bb[4];
  #pragma unroll
  for (int j = 0; j < 4; ++j) {
    int bi = (int)((x[j] - LOv) * SCv);
    bi = bi < 0 ? 0 : (bi > NBv - 1 ? NBv - 1 : bi);
    bb[j] = bi;
    atomicAdd(&pref[swz(bi)], 1);
  }
  __syncthreads();

  // exclusive prefix over 2048 bins (8/thread)
  {
    int base_ = tid * 8;
    int loc[8]; int s = 0;
    #pragma unroll
    for (int j = 0; j < 8; ++j) loc[j] = pref[swz(base_ + j)];
    #pragma unroll
    for (int j = 0; j < 8; ++j) { int c = loc[j]; loc[j] = s; s += c; }
    int inc = s;
    #pragma unroll
    for (int off = 1; off < 64; off <<= 1) {
      int o = __shfl_up(inc, off, 64);
      if (lane >= off) inc += o;
    }
    if (lane == 63) wsum[wv] = inc;
    __syncthreads();
    int wbase = 0;
    #pragma unroll
    for (int ww = 0; ww < 4; ++ww) if (ww < wv) wbase += wsum[ww];
    int tbase = wbase + inc - s;
    #pragma unroll
    for (int j = 0; j < 8; ++j) pref[swz(base_ + j)] = tbase + loc[j];
  }
  __syncthreads();

  // scatter (value, orig idx)
  #pragma unroll
  for (int j = 0; j < 4; ++j) {
    int p = atomicAdd(&pref[swz(bb[j])], 1);
    skey[p] = x[j];
    sidx[p] = (unsigned short)(tid + 256 * j);
  }
  __syncthreads();

  // position-ordered exact rank (stable: (value, orig idx)) + stencil scatter
  #pragma unroll
  for (int k = 0; k < 4; ++k) {
    int p = tid + 256 * k;
    float y = skey[p];
    int m = sidx[p];
    int b = (int)((y - LOv) * SCv);
    b = b < 0 ? 0 : (b > NBv - 1 ? NBv - 1 : b);
    int lo_ = b ? pref[swz(b - 1)] : 0;
    int hi_ = pref[swz(b)];
    int r = lo_;
    for (int q = lo_; q < hi_; ++q) {
      float z = skey[q];
      r += (z < y || (z == y && sidx[q] < m)) ? 1 : 0;
    }
    // element with original index m has rank r in the stable argsort
    float wvv = weight[(size_t)l * Mc + r];
    double pos = (double)(m + 1) * (double)(Nc + 1) / (double)(Mc + 1) - 1.0;
    int i0 = (int)pos;
    float t = (float)(pos - (double)i0);
    atomicAdd(&vrow[i0], (1.0f - t) * wvv);
    atomicAdd(&vrow[i0 + 1], t * wvv);
  }
  __syncthreads();
  for (int i = tid; i < Nc; i += 256) v[(size_t)l * Nc + i] = vrow[i];
}

// ---------------------------------------------------------------------------
// Kernel 2: MFMA GEMM, f32 = bf16 hi + lo (3-term).
//  512 threads = 8 waves; wave wv owns 16 n-rows x 128 l.
//  A: lane loads its row-slices once up-front (coalesced), converts per
//  chunk in-register. B: double-buffered LDS; one barrier per chunk.
// sl[bloc][l][n] = sum_d X[bloc,n,d] * W[l,d]
// ---------------------------------------------------------------------------
__global__ __launch_bounds__(512) void gemm_kernel(
    const float* __restrict__ X, const unsigned short* __restrict__ Whp,
    const unsigned short* __restrict__ Wlp, float* __restrict__ sl) {
  __shared__ unsigned short Bh[2][128][40];  // 20 KB
  __shared__ unsigned short Bl[2][128][40];  // 20 KB

  int bloc = blockIdx.y;
  int nbase = blockIdx.x * 128;
  int tid = threadIdx.x;
  int lane = tid & 63;
  int wv = tid >> 6;       // wave 0..7 -> 16 n-rows each
  int m16 = lane & 15;
  int kg = lane >> 4;

  // B staging: one 8-u16 segment per thread per array
  int brow = tid >> 2;
  int bc = (tid & 3) * 8;
  const unsigned short* gbh = Whp + (size_t)brow * Dc + bc;
  const unsigned short* gbl = Wlp + (size_t)brow * Dc + bc;

  // ---- A: full kg-slice of the lane's row, all 4 chunks, up-front
  const float* arow = X + ((size_t)bloc * Nc + nbase + wv * 16 + m16) * Dc + kg * 8;
  float4 af[4][2];
  #pragma unroll
  for (int c = 0; c < 4; ++c) {
    af[c][0] = *(const float4*)(arow + c * 32);
    af[c][1] = *(const float4*)(arow + c * 32 + 4);
  }

  // prologue: B chunk 0 -> buf0; B chunk 1 -> regs
  ushort8v rbh = *(const ushort8v*)gbh;
  ushort8v rbl = *(const ushort8v*)gbl;
  *(ushort8v*)&Bh[0][brow][bc] = rbh;
  *(ushort8v*)&Bl[0][brow][bc] = rbl;
  rbh = *(const ushort8v*)(gbh + 32);
  rbl = *(const ushort8v*)(gbl + 32);

  f32x4 acc[8] = {};
  __syncthreads();  // buf0 visible

  #pragma unroll
  for (int c = 0; c < 4; ++c) {
    if (c < 3) {
      *(ushort8v*)&Bh[(c + 1) & 1][brow][bc] = rbh;
      *(ushort8v*)&Bl[(c + 1) & 1][brow][bc] = rbl;
    }
    if (c < 2) {
      rbh = *(const ushort8v*)(gbh + (c + 2) * 32);
      rbl = *(const ushort8v*)(gbl + (c + 2) * 32);
    }

    // convert A chunk c
    float xs[8] = {af[c][0].x, af[c][0].y, af[c][0].z, af[c][0].w,
                   af[c][1].x, af[c][1].y, af[c][1].z, af[c][1].w};
    short8 ah, al;
    #pragma unroll
    for (int e = 0; e < 8; ++e) {
      unsigned short h = f2bf(xs[e]);
      ah[e] = (short)h;
      al[e] = (short)f2bf(xs[e] - bf2f(h));
    }

    #pragma unroll
    for (int u = 0; u < 8; ++u) {
      short8 bh = *(const short8*)&Bh[c & 1][u * 16 + m16][kg * 8];
      short8 bl = *(const short8*)&Bl[c & 1][u * 16 + m16][kg * 8];
      acc[u] = __builtin_amdgcn_mfma_f32_16x16x32_bf16(ah, bh, acc[u], 0, 0, 0);
      acc[u] = __builtin_amdgcn_mfma_f32_16x16x32_bf16(ah, bl, acc[u], 0, 0, 0);
      acc[u] = __builtin_amdgcn_mfma_f32_16x16x32_bf16(al, bh, acc[u], 0, 0, 0);
    }
    __syncthreads();
  }

  // write-out: C/D col = m16 (l), row = kg*4 + reg (n)
  #pragma unroll
  for (int u = 0; u < 8; ++u) {
    int l = u * 16 + m16;
    int n0 = nbase + wv * 16 + kg * 4;
    float* dst = sl + ((size_t)bloc * Lc + l) * Nc + n0;
    *(float4*)dst = *(float4*)&acc[u];
  }
}

// ---------------------------------------------------------------------------
// Kernel 3 (v9): radix-rank + fused dot, 512 threads.
//  VECTORIZED inner rank loop (ds_read_b128): by monotonicity of the bin
//  map, candidates before the segment are automatically counted (z<y) and
//  candidates after it automatically not (z>y) -> scan aligned float4
//  blocks covering [lo,hi) with NO masking:
//     r = lo&~3;  for q4 in [lo>>2, (hi+3)>>2): r += sum_i pred(z4[i], 4q4+i)
//  4x fewer LDS issues + 4x less loop overhead in the hot loop.
// ---------------------------------------------------------------------------
__device__ __forceinline__ int gbin(float x) {
  constexpr int NB = 4096;
  // NB / (1 + exp(-1.702 x)) = NB / (1 + exp2(-2.45541 x))  (monotone)
  float t = __builtin_amdgcn_exp2f(x * -2.45541f);
  float r = __builtin_amdgcn_rcpf(1.0f + t);
  int bi = (int)((float)NB * r);
  return bi < 0 ? 0 : (bi > NB - 1 ? NB - 1 : bi);
}

__global__ __launch_bounds__(512, 8) void rank_dot_kernel(
    const float* __restrict__ sl, const float* __restrict__ v,
    const float* __restrict__ C, float* __restrict__ out, int b0) {
  constexpr int NB = 4096;
  constexpr int NT = 512;
  constexpr int EL = Nc / NT;  // 8 elements per thread

  __shared__ int pref[NB];                   // hist -> EXCLUSIVE prefix; then red
  __shared__ __align__(16) float skey[Nc];   // (wsum during scan) bin-ordered keys
  int* wsum = (int*)skey;        // live only during scan (before skey writes)
  float* red = (float*)pref;     // live only after final barrier

  int l = blockIdx.x & (Lc - 1);
  int bloc = blockIdx.x >> 7;
  int tid = threadIdx.x;
  const float* src = sl + ((size_t)bloc * Lc + l) * Nc;

  // coalesced strided load: thread owns float4s {tid + 512*j}
  float x[EL];
  {
    const float4* s4 = (const float4*)src;
    #pragma unroll
    for (int j = 0; j < EL / 4; ++j) {
      float4 f = s4[tid + NT * j];
      x[j * 4 + 0] = f.x; x[j * 4 + 1] = f.y;
      x[j * 4 + 2] = f.z; x[j * 4 + 3] = f.w;
    }
  }

  for (int i = tid; i < NB; i += NT) pref[i] = 0;
  __syncthreads();

  // histogram; returned old count = within-bin slot
  int bb[EL];
  int ofs[EL];
  #pragma unroll
  for (int j = 0; j < EL; ++j) {
    int bi = gbin(x[j]);
    bb[j] = bi;
    ofs[j] = atomicAdd(&pref[swz(bi)], 1);
  }
  __syncthreads();

  // exclusive prefix sum over 4096 bins (8 bins/thread)
  {
    int base_ = tid * 8;
    int loc[8]; int s = 0;
    #pragma unroll
    for (int j = 0; j < 8; ++j) loc[j] = pref[swz(base_ + j)];
    #pragma unroll
    for (int j = 0; j < 8; ++j) { int c = loc[j]; loc[j] = s; s += c; }
    int lane = tid & 63, wvv = tid >> 6;
    int inc = s;
    #pragma unroll
    for (int off = 1; off < 64; off <<= 1) {
      int o = __shfl_up(inc, off, 64);
      if (lane >= off) inc += o;
    }
    if (lane == 63) wsum[wvv] = inc;
    __syncthreads();
    int wbase = 0;
    #pragma unroll
    for (int ww = 0; ww < 8; ++ww) if (ww < wvv) wbase += wsum[ww];
    int tbase = wbase + inc - s;  // exclusive across threads
    #pragma unroll
    for (int j = 0; j < 8; ++j) pref[swz(base_ + j)] = tbase + loc[j];
  }
  __syncthreads();

  // scatter: pos = exclusive-prefix + slot (no second atomic; pref unchanged)
  #pragma unroll
  for (int j = 0; j < EL; ++j) {
    skey[pref[swz(bb[j])] + ofs[j]] = x[j];
  }
  __syncthreads();

  // POSITION-ORDERED rank + fused dot over aligned float4 blocks.
  // Bin recomputed from value (pure function -> consistent). Candidates in
  // earlier bins are automatically z<y (counted, and the alignment slack
  // [alo,lo) is exactly compensated by starting r at alo); later bins are
  // automatically z>y (not counted). Tie-break q<p within equal values:
  // bijective; ties are bitwise-equal so the dot sum is deterministic.
  const f32x4* skey4 = (const f32x4*)skey;
  const float* vrow = v + (size_t)l * Nc;
  float acc = 0.f;
  #pragma unroll
  for (int k = 0; k < EL; ++k) {
    int p = tid + NT * k;
    float y = skey[p];
    int b = gbin(y);
    int lo_ = pref[swz(b)];
    int hi_ = (b == NB - 1) ? Nc : pref[swz(b + 1)];
    int q4 = lo_ >> 2;
    int e4 = (hi_ + 3) >> 2;
    int r = q4 << 2;
    for (; q4 < e4; ++q4) {
      f32x4 z = skey4[q4];
      int qb = q4 << 2;
      r += (z[0] < y || (z[0] == y && qb + 0 < p)) ? 1 : 0;
      r += (z[1] < y || (z[1] == y && qb + 1 < p)) ? 1 : 0;
      r += (z[2] < y || (z[2] == y && qb + 2 < p)) ? 1 : 0;
      r += (z[3] < y || (z[3] == y && qb + 3 < p)) ? 1 : 0;
    }
    acc += y * vrow[r];
  }

  #pragma unroll
  for (int off = 1; off < 64; off <<= 1) acc += __shfl_xor(acc, off, 64);
  __syncthreads();  // all pref reads done before red (aliased) is written
  if ((tid & 63) == 0) red[tid >> 6] = acc;
  __syncthreads();
  if (tid == 0) {
    float t = 0.f;
    #pragma unroll
    for (int ww = 0; ww < 8; ++ww) t += red[ww];
    int b = b0 + bloc;
    out[(size_t)b * Lc + l] = C[l] - t;
  }
}

// ---------------------------------------------------------------------------
extern "C" void kernel_launch(void* const* d_in, const int* in_sizes, int n_in,
                              void* d_out, int out_size, void* d_ws, size_t ws_size,
                              hipStream_t stream) {
  const float* X       = (const float*)d_in[0];  // [B,N,D]
  const float* theta_v = (const float*)d_in[1];  // [L,D]
  const float* ref     = (const float*)d_in[2];  // [M,L]
  const float* weight  = (const float*)d_in[3];  // [L,M]
  float* out = (float*)d_out;                    // [B,L]

  // workspace layout: v [L*N] f32 | Wh,Wl [L*D] u16 | C [128] f32 | sl
  float* v  = (float*)d_ws;
  unsigned short* Wh = (unsigned short*)(v + (size_t)Lc * Nc);
  unsigned short* Wl = Wh + (size_t)Lc * Dc;
  float* Cc = (float*)(Wl + (size_t)Lc * Dc);
  float* sl = Cc + 128;
  size_t used = (size_t)((char*)sl - (char*)d_ws);
  size_t per_b = (size_t)Lc * Nc * sizeof(float);  // 2 MB per batch element
  int chunk = 1;
  if (ws_size > used + per_b) {
    size_t c = (ws_size - used) / per_b;
    chunk = (int)(c > (size_t)Bc ? (size_t)Bc : c);
    if (chunk < 1) chunk = 1;
  }

  setup_kernel<<<Lc, 256, 0, stream>>>(theta_v, ref, weight, Wh, Wl, Cc, v);

  for (int b0 = 0; b0 < Bc; b0 += chunk) {
    int nb = (Bc - b0) < chunk ? (Bc - b0) : chunk;
    dim3 g1(Nc / 128, nb);
    gemm_kernel<<<g1, 512, 0, stream>>>(X + (size_t)b0 * Nc * Dc, Wh, Wl, sl);
    rank_dot_kernel<<<(size_t)nb * Lc, 512, 0, stream>>>(sl, v, Cc, out, b0);
  }
}